// Round 1
// baseline (251.080 us; speedup 1.0000x reference)
//
#include <hip/hip_runtime.h>

// Problem constants (fixed by setup_inputs)
#define BATCH   8
#define CIN     256
#define HH      64
#define WW      64
#define HW      (HH*WW)          // 4096
#define COUT    256
#define NEXP    8
#define KTOP    2
#define NPAIR   (BATCH*KTOP)     // 16
#define CIN_PE  32               // in-channels per expert (Cin/groups)
#define NG      8                // GroupNorm groups
#define CPG     (COUT/NG)        // 32 channels per GN group
#define KTAPS   288              // 32*9
#define EPSV    1e-5f

// ws layout (floats):
//   conv buffer : [NPAIR][COUT][HW]  = 16*256*4096 = 16,777,216
//   wT          : [NEXP][288][COUT]  = 589,824
//   stats       : [NPAIR][NG][2]     = 256
#define WS_CONV_OFF  0
#define WS_WT_OFF    16777216
#define WS_STATS_OFF (16777216 + 589824)

// ---------------------------------------------------------------------------
// Kernel 0: transpose conv_w [e*256+c][i][tap] -> wT [e][i*9+tap][c]
// ---------------------------------------------------------------------------
__global__ void wtrans_kernel(const float* __restrict__ w, float* __restrict__ wT) {
    int idx = blockIdx.x * 256 + threadIdx.x;       // over e,it,c with c fastest
    if (idx >= NEXP * KTAPS * COUT) return;
    int c   = idx & 255;
    int eit = idx >> 8;          // e*288 + it
    int it  = eit % KTAPS;
    int e   = eit / KTAPS;
    wT[idx] = w[(size_t)(e * COUT + c) * KTAPS + it];
}

// ---------------------------------------------------------------------------
// Kernel 1: conv for the 16 selected (b,k) pairs + partial GN stats
// Block: 256 threads. Tile: 64 out-ch x 4 rows x 64 cols.
// Thread: 8 out-ch x 1 row x 8 cols (64 fp32 accumulators).
// ---------------------------------------------------------------------------
__launch_bounds__(256, 2)
__global__ void conv_kernel(const float* __restrict__ x,
                            const int*   __restrict__ ridx,
                            const float* __restrict__ wT,
                            float* __restrict__ convout,
                            float* __restrict__ stats)
{
    __shared__ float xs[8][6][68];       // 8 in-ch, 6 rows (halo), 66 used cols (pad->68)
    __shared__ float wls[8 * 9 * 64];    // 8 in-ch x 9 taps x 64 out-ch
    __shared__ float red[2][2];          // [group-in-tile][sum,sumsq]

    const int tid     = threadIdx.x;
    const int rowtile = blockIdx.x;          // 16 tiles of 4 rows
    const int c0      = blockIdx.y * 64;     // out-channel tile base
    const int p       = blockIdx.z;          // pair index = b*KTOP+k
    const int b       = p / KTOP;
    const int e       = ridx[p];

    const int r0   = rowtile * 4;
    const float* xbase = x + ((size_t)b * CIN + e * CIN_PE) * HW;
    const float* wbase = wT + (size_t)e * KTAPS * COUT + c0;

    const int tc   = tid & 7;          // out-channel sub-tile 0..7 (8 ch each)
    const int ts   = tid >> 3;         // 0..31
    const int row  = ts >> 3;          // 0..3
    const int col0 = (ts & 7) * 8;     // 0..56

    float acc[8][8];
    #pragma unroll
    for (int a = 0; a < 8; ++a)
        #pragma unroll
        for (int q = 0; q < 8; ++q) acc[a][q] = 0.f;

    if (tid < 4) ((float*)red)[tid] = 0.f;

    for (int i0 = 0; i0 < CIN_PE; i0 += 8) {
        __syncthreads();
        // stage x tile: 8 ch x 6 rows x 66 cols (zero-padded borders)
        for (int idx = tid; idx < 8 * 6 * 66; idx += 256) {
            int i   = idx / 396;
            int rem = idx - i * 396;
            int r   = rem / 66;
            int c   = rem - r * 66;
            int gy  = r0 - 1 + r;
            int gx  = c - 1;
            float v = 0.f;
            if ((unsigned)gy < 64u && (unsigned)gx < 64u)
                v = xbase[(size_t)(i0 + i) * HW + gy * 64 + gx];
            xs[i][r][c] = v;
        }
        // stage w tile: 8 ch x 9 taps x 64 out-ch (coalesced from wT)
        for (int idx = tid; idx < 8 * 9 * 64; idx += 256) {
            int i   = idx / 576;
            int rem = idx - i * 576;           // tap*64 + cl
            wls[idx] = wbase[((size_t)(i0 + i) * 9 + (rem >> 6)) * COUT + (rem & 63)];
        }
        __syncthreads();

        #pragma unroll
        for (int i = 0; i < 8; ++i) {
            #pragma unroll
            for (int dy = 0; dy < 3; ++dy) {
                const float* xr = &xs[i][row + dy][col0];
                float4 xa = *(const float4*)(xr);
                float4 xb = *(const float4*)(xr + 4);
                float2 xc = *(const float2*)(xr + 8);
                float xv[10] = {xa.x, xa.y, xa.z, xa.w,
                                xb.x, xb.y, xb.z, xb.w,
                                xc.x, xc.y};
                #pragma unroll
                for (int dx = 0; dx < 3; ++dx) {
                    const float* wr = &wls[(i * 9 + dy * 3 + dx) * 64 + tc * 8];
                    float4 w0 = *(const float4*)(wr);
                    float4 w1 = *(const float4*)(wr + 4);
                    float wv[8] = {w0.x, w0.y, w0.z, w0.w, w1.x, w1.y, w1.z, w1.w};
                    #pragma unroll
                    for (int cc = 0; cc < 8; ++cc)
                        #pragma unroll
                        for (int cx = 0; cx < 8; ++cx)
                            acc[cc][cx] = fmaf(wv[cc], xv[cx + dx], acc[cc][cx]);
                }
            }
        }
    }

    // write conv outputs + accumulate this thread's GN partial stats
    float s = 0.f, sq = 0.f;
    #pragma unroll
    for (int cc = 0; cc < 8; ++cc) {
        float* ob = convout + ((size_t)p * COUT + c0 + tc * 8 + cc) * HW
                            + (r0 + row) * 64 + col0;
        *(float4*)(ob)     = make_float4(acc[cc][0], acc[cc][1], acc[cc][2], acc[cc][3]);
        *(float4*)(ob + 4) = make_float4(acc[cc][4], acc[cc][5], acc[cc][6], acc[cc][7]);
        #pragma unroll
        for (int cx = 0; cx < 8; ++cx) {
            float v = acc[cc][cx];
            s += v;
            sq = fmaf(v, v, sq);
        }
    }
    // per-block group reduction (thread's 8 channels lie in one GN group)
    int gloc = tc >> 2;
    atomicAdd(&red[gloc][0], s);
    atomicAdd(&red[gloc][1], sq);
    __syncthreads();
    if (tid < 2) {
        int gglob = blockIdx.y * 2 + tid;
        atomicAdd(&stats[((size_t)p * NG + gglob) * 2 + 0], red[tid][0]);
        atomicAdd(&stats[((size_t)p * NG + gglob) * 2 + 1], red[tid][1]);
    }
}

// ---------------------------------------------------------------------------
// Kernel 2: GroupNorm + affine + SiLU + weighted top-k combine
// Block: 256 threads, one (b, c, 16-row tile); thread: one float4.
// ---------------------------------------------------------------------------
__global__ void finalize_kernel(const float* __restrict__ conv,
                                const float* __restrict__ stats,
                                const int*   __restrict__ ridx,
                                const float* __restrict__ rw,
                                const float* __restrict__ gamma,
                                const float* __restrict__ beta,
                                float* __restrict__ out)
{
    const int tid     = threadIdx.x;
    const int rowtile = blockIdx.x;    // 0..3
    const int c       = blockIdx.y;    // 0..255
    const int b       = blockIdx.z;    // 0..7
    const int g       = c >> 5;
    const int sp      = rowtile * 1024 + tid * 4;

    float r0 = 0.f, r1 = 0.f, r2 = 0.f, r3 = 0.f;
    #pragma unroll
    for (int k = 0; k < KTOP; ++k) {
        int   p  = b * KTOP + k;
        int   e  = ridx[p];
        float wk = rw[p];
        float s  = stats[((size_t)p * NG + g) * 2 + 0];
        float sq = stats[((size_t)p * NG + g) * 2 + 1];
        const float cnt = 1.f / (float)(CPG * HW);   // 1/131072
        float mu  = s * cnt;
        float var = fmaf(-mu, mu, sq * cnt);
        float inv = rsqrtf(var + EPSV);
        float ga  = gamma[e * COUT + c] * inv;
        float be  = fmaf(-mu, ga, beta[e * COUT + c]);
        float4 v = *(const float4*)&conv[((size_t)p * COUT + c) * HW + sp];
        float n0 = fmaf(v.x, ga, be);
        float n1 = fmaf(v.y, ga, be);
        float n2 = fmaf(v.z, ga, be);
        float n3 = fmaf(v.w, ga, be);
        r0 = fmaf(wk * n0, 1.f / (1.f + __expf(-n0)), r0);
        r1 = fmaf(wk * n1, 1.f / (1.f + __expf(-n1)), r1);
        r2 = fmaf(wk * n2, 1.f / (1.f + __expf(-n2)), r2);
        r3 = fmaf(wk * n3, 1.f / (1.f + __expf(-n3)), r3);
    }
    *(float4*)&out[((size_t)b * COUT + c) * HW + sp] = make_float4(r0, r1, r2, r3);
}

// ---------------------------------------------------------------------------
extern "C" void kernel_launch(void* const* d_in, const int* in_sizes, int n_in,
                              void* d_out, int out_size, void* d_ws, size_t ws_size,
                              hipStream_t stream) {
    const float* x      = (const float*)d_in[0];
    const float* rw     = (const float*)d_in[1];
    const int*   ridx   = (const int*)  d_in[2];
    // d_in[3] = top_k (known == 2)
    const float* conv_w = (const float*)d_in[4];
    const float* gamma  = (const float*)d_in[5];
    const float* beta   = (const float*)d_in[6];
    float* out = (float*)d_out;

    float* ws      = (float*)d_ws;
    float* convbuf = ws + WS_CONV_OFF;
    float* wT      = ws + WS_WT_OFF;
    float* stats   = ws + WS_STATS_OFF;

    hipMemsetAsync(stats, 0, NPAIR * NG * 2 * sizeof(float), stream);

    hipLaunchKernelGGL(wtrans_kernel, dim3((NEXP * KTAPS * COUT + 255) / 256), dim3(256),
                       0, stream, conv_w, wT);

    hipLaunchKernelGGL(conv_kernel, dim3(16, 4, NPAIR), dim3(256),
                       0, stream, x, ridx, wT, convbuf, stats);

    hipLaunchKernelGGL(finalize_kernel, dim3(4, COUT, BATCH), dim3(256),
                       0, stream, convbuf, stats, ridx, rw, gamma, beta, out);
}

// Round 2
// 175.231 us; speedup vs baseline: 1.4329x; 1.4329x over previous
//
#include <hip/hip_runtime.h>

typedef __attribute__((ext_vector_type(8))) short bf8_t;   // 8 bf16 in 4 VGPRs
typedef __attribute__((ext_vector_type(4))) float f4_t;

#define BATCH 8
#define HW    4096
#define COUT  256
#define KTOP  2
#define NPAIR 16
#define NG    8
#define EPSV  1e-5f

// ws layout (float units):
//  convbuf (ushort): 16*256*4096            -> 8,388,608 f
//  xtp     (ushort): 16*66*66*32            -> 1,115,136 f
//  wTb     (ushort): 8*9*256*32             ->   294,912 f
//  stats   (float) : 16*8*2                 ->       256 f
// total ~39 MB (round-1 used ~70 MB, so ws is big enough)
#define OFF_CONV  0
#define OFF_XTP   8388608
#define OFF_WTB   (8388608 + 1115136)
#define OFF_STATS (8388608 + 1115136 + 294912)

__device__ __forceinline__ unsigned short f2bf(float f) {
    unsigned u = __builtin_bit_cast(unsigned, f);
    u = (u + 0x7FFFu + ((u >> 16) & 1u)) >> 16;
    return (unsigned short)u;
}
__device__ __forceinline__ float bf2f(unsigned short h) {
    return __builtin_bit_cast(float, (unsigned)h << 16);
}

// ---------------------------------------------------------------------------
// prep_w: conv_w [e*256+c][i(32)][ky][kx] fp32 -> wTb[e][tap][cout][i] bf16
// (fragment-ready: 8 consecutive i per lane-octet)
// ---------------------------------------------------------------------------
__global__ void prep_w(const float* __restrict__ w, unsigned short* __restrict__ wTb) {
    int idx = blockIdx.x * 256 + threadIdx.x;          // = ((e*9+tap)*256 + c)*32 + i
    if (idx >= 8 * 9 * 256 * 32) return;
    int i   = idx & 31;
    int c   = (idx >> 5) & 255;
    int et  = idx >> 13;            // e*9 + tap
    int tap = et % 9;
    int e   = et / 9;
    wTb[idx] = f2bf(w[((size_t)(e * 256 + c) * 32 + i) * 9 + tap]);
}

// ---------------------------------------------------------------------------
// prep_x: gather selected expert slice, transpose to xtp[p][row][col][ch32]
// bf16 with halo zeros (rows/cols 0 and 65). One block = one (p, padded row).
// ---------------------------------------------------------------------------
__global__ void prep_x(const float* __restrict__ x, const int* __restrict__ ridx,
                       unsigned short* __restrict__ xtp) {
    __shared__ float t[32][65];
    const int r   = blockIdx.x;       // 0..65 padded row
    const int p   = blockIdx.y;       // 0..15
    const int b   = p >> 1;
    const int e   = ridx[p];
    const int tid = threadIdx.x;
    const bool inter = (r >= 1 && r <= 64);
    if (inter) {
        const float* xb = x + (((size_t)b * 256 + e * 32) * 64 + (r - 1)) * 64;
        for (int f = tid; f < 2048; f += 256)
            t[f >> 6][f & 63] = xb[(size_t)(f >> 6) * 4096 + (f & 63)];
    }
    __syncthreads();
    unsigned short* ob = xtp + ((size_t)p * 66 + r) * 66 * 32;
    for (int f = tid; f < 1056; f += 256) {            // 66 cols x 16 ch-pairs
        int c = f >> 4, chp = f & 15;
        ushort2 v = make_ushort2(0, 0);
        if (inter && c >= 1 && c <= 64)
            v = make_ushort2(f2bf(t[2 * chp][c - 1]), f2bf(t[2 * chp + 1][c - 1]));
        *(ushort2*)(ob + c * 32 + chp * 2) = v;
    }
}

// ---------------------------------------------------------------------------
// conv_mfma: per block = 128 cout x (2 rows x 64 cols), 4 waves of 64x64.
// K = 288 ordered as 9 taps x 32 in-ch. x tile staged ONCE in LDS; each tap's
// im2col B-tile is a shifted window of it. A-frags load straight from L2.
// Barrier-free K-loop. Fused per-group GN partial stats via shuffle+atomics.
// ---------------------------------------------------------------------------
__launch_bounds__(256, 2)
__global__ void conv_mfma(const unsigned short* __restrict__ xtp,
                          const unsigned short* __restrict__ wTb,
                          const int* __restrict__ ridx,
                          unsigned short* __restrict__ convbuf,
                          float* __restrict__ stats)
{
    __shared__ short xs[4 * 66 * 32];      // 4 rows x 66 cols x 32 ch bf16 (16.9 KB)

    const int tid = threadIdx.x;
    const int st  = blockIdx.x;            // 0..31 spatial tile (2 output rows)
    const int ct  = blockIdx.y;            // 0..1  cout tile (128 couts)
    const int p   = blockIdx.z;            // 0..15 pair
    const int e   = ridx[p];

    // stage x tile: xtp rows [st*2, st*2+4) are exactly contiguous -> linear copy
    {
        const unsigned short* g = xtp + ((size_t)p * 66 + st * 2) * 66 * 32;
        for (int f = tid; f < 1056; f += 256)
            *(bf8_t*)&xs[f * 8] = *(const bf8_t*)(g + f * 8);
    }
    __syncthreads();

    const int lane = tid & 63;
    const int l15  = lane & 15;
    const int oct  = lane >> 4;            // 0..3
    const int wave = tid >> 6;             // 0..3
    const int wm   = wave >> 1;            // cout-wave
    const int wn   = wave & 1;             // row-wave

    // per-lane bases (element units)
    const short* Bbase = xs + wn * 2112 + l15 * 32 + oct * 8;
    const unsigned short* Abase =
        wTb + ((size_t)e * 9 * 256 + ct * 128 + wm * 64 + l15) * 32 + oct * 8;

    f4_t acc[4][4];
    #pragma unroll
    for (int mi = 0; mi < 4; ++mi)
        #pragma unroll
        for (int ni = 0; ni < 4; ++ni)
            acc[mi][ni] = (f4_t){0.f, 0.f, 0.f, 0.f};

    #pragma unroll
    for (int tap = 0; tap < 9; ++tap) {
        const int dy = tap / 3, dx = tap % 3;
        bf8_t af[4], bfr[4];
        #pragma unroll
        for (int mi = 0; mi < 4; ++mi)
            af[mi] = *(const bf8_t*)(Abase + tap * 8192 + mi * 512);
        #pragma unroll
        for (int ni = 0; ni < 4; ++ni)
            bfr[ni] = *(const bf8_t*)(Bbase + dy * 2112 + dx * 32 + ni * 512);
        #pragma unroll
        for (int mi = 0; mi < 4; ++mi)
            #pragma unroll
            for (int ni = 0; ni < 4; ++ni)
                acc[mi][ni] = __builtin_amdgcn_mfma_f32_16x16x32_bf16(
                    af[mi], bfr[ni], acc[mi][ni], 0, 0, 0);
    }

    // epilogue: bf16 store + GN partial stats
    const size_t cbase  = ((size_t)p * 256 + ct * 128 + wm * 64) * 4096;
    const int    spbase = (st * 2 + wn) * 64;
    float s0 = 0.f, q0 = 0.f, s1 = 0.f, q1 = 0.f;
    #pragma unroll
    for (int mi = 0; mi < 4; ++mi) {
        #pragma unroll
        for (int ni = 0; ni < 4; ++ni) {
            #pragma unroll
            for (int r = 0; r < 4; ++r) {
                float v = acc[mi][ni][r];
                int cout_loc = mi * 16 + oct * 4 + r;
                convbuf[cbase + (size_t)cout_loc * 4096 + spbase + ni * 16 + l15] = f2bf(v);
                if (mi < 2) { s0 += v; q0 = fmaf(v, v, q0); }
                else        { s1 += v; q1 = fmaf(v, v, q1); }
            }
        }
    }
    #pragma unroll
    for (int m = 32; m >= 1; m >>= 1) {
        s0 += __shfl_xor(s0, m); q0 += __shfl_xor(q0, m);
        s1 += __shfl_xor(s1, m); q1 += __shfl_xor(q1, m);
    }
    if (lane == 0) {
        int g0 = ct * 4 + wm * 2;
        atomicAdd(&stats[(p * 8 + g0) * 2 + 0], s0);
        atomicAdd(&stats[(p * 8 + g0) * 2 + 1], q0);
        atomicAdd(&stats[(p * 8 + g0 + 1) * 2 + 0], s1);
        atomicAdd(&stats[(p * 8 + g0 + 1) * 2 + 1], q1);
    }
}

// ---------------------------------------------------------------------------
// finalize: GroupNorm (from stats) + affine + SiLU + weighted top-k combine
// ---------------------------------------------------------------------------
__global__ void finalize_k(const unsigned short* __restrict__ conv,
                           const float* __restrict__ stats,
                           const int* __restrict__ ridx,
                           const float* __restrict__ rw,
                           const float* __restrict__ gamma,
                           const float* __restrict__ beta,
                           float* __restrict__ out)
{
    const int tid = threadIdx.x;
    const int rt  = blockIdx.x;        // 0..3
    const int c   = blockIdx.y;        // 0..255
    const int b   = blockIdx.z;        // 0..7
    const int g   = c >> 5;
    const int sp  = rt * 1024 + tid * 4;

    float r0 = 0.f, r1 = 0.f, r2 = 0.f, r3 = 0.f;
    #pragma unroll
    for (int k = 0; k < KTOP; ++k) {
        int   p  = b * KTOP + k;
        int   e  = ridx[p];
        float wk = rw[p];
        float s  = stats[(p * 8 + g) * 2 + 0];
        float sq = stats[(p * 8 + g) * 2 + 1];
        const float cnt = 1.f / 131072.f;
        float mu  = s * cnt;
        float var = fmaf(-mu, mu, sq * cnt);
        float inv = rsqrtf(var + EPSV);
        float ga  = gamma[e * 256 + c] * inv;
        float be  = fmaf(-mu, ga, beta[e * 256 + c]);
        ushort4 v = *(const ushort4*)&conv[((size_t)p * 256 + c) * 4096 + sp];
        float n0 = fmaf(bf2f(v.x), ga, be);
        float n1 = fmaf(bf2f(v.y), ga, be);
        float n2 = fmaf(bf2f(v.z), ga, be);
        float n3 = fmaf(bf2f(v.w), ga, be);
        r0 = fmaf(wk * n0, 1.f / (1.f + __expf(-n0)), r0);
        r1 = fmaf(wk * n1, 1.f / (1.f + __expf(-n1)), r1);
        r2 = fmaf(wk * n2, 1.f / (1.f + __expf(-n2)), r2);
        r3 = fmaf(wk * n3, 1.f / (1.f + __expf(-n3)), r3);
    }
    *(float4*)&out[((size_t)b * 256 + c) * 4096 + sp] = make_float4(r0, r1, r2, r3);
}

// ---------------------------------------------------------------------------
extern "C" void kernel_launch(void* const* d_in, const int* in_sizes, int n_in,
                              void* d_out, int out_size, void* d_ws, size_t ws_size,
                              hipStream_t stream) {
    const float* x      = (const float*)d_in[0];
    const float* rw     = (const float*)d_in[1];
    const int*   ridx   = (const int*)  d_in[2];
    const float* conv_w = (const float*)d_in[4];
    const float* gamma  = (const float*)d_in[5];
    const float* beta   = (const float*)d_in[6];
    float* out = (float*)d_out;

    float* ws = (float*)d_ws;
    unsigned short* convbuf = (unsigned short*)(ws + OFF_CONV);
    unsigned short* xtp     = (unsigned short*)(ws + OFF_XTP);
    unsigned short* wTb     = (unsigned short*)(ws + OFF_WTB);
    float*          stats   = ws + OFF_STATS;

    hipMemsetAsync(stats, 0, NPAIR * NG * 2 * sizeof(float), stream);

    hipLaunchKernelGGL(prep_w, dim3(2304), dim3(256), 0, stream, conv_w, wTb);
    hipLaunchKernelGGL(prep_x, dim3(66, 16), dim3(256), 0, stream, x, ridx, xtp);
    hipLaunchKernelGGL(conv_mfma, dim3(32, 2, 16), dim3(256), 0, stream,
                       xtp, wTb, ridx, convbuf, stats);
    hipLaunchKernelGGL(finalize_k, dim3(4, 256, 8), dim3(256), 0, stream,
                       convbuf, stats, ridx, rw, gamma, beta, out);
}

// Round 3
// 162.491 us; speedup vs baseline: 1.5452x; 1.0784x over previous
//
#include <hip/hip_runtime.h>

typedef __attribute__((ext_vector_type(8))) short bf8_t;   // 8 bf16 (4 VGPRs)
typedef __attribute__((ext_vector_type(4))) float f4_t;

#define BATCH 8
#define HW    4096
#define COUT  256
#define KTOP  2
#define NPAIR 16
#define NG    8
#define EPSV  1e-5f
#define XSTR  40            // padded elems per (row,col) cell: 80B -> uniform LDS banks

// ws layout (float units):
//  convbuf (ushort): 16*256*4096   = 16,777,216 us -> 8,388,608 f
//  xtp     (ushort): 16*66*66*40   =  2,787,840 us -> 1,393,920 f
//  wTb     (ushort): 8*9*256*32    =    589,824 us ->   294,912 f
//  stats   (float) : 16*8*2        =        256 f
#define OFF_CONV  0
#define OFF_XTP   8388608
#define OFF_WTB   (8388608 + 1393920)
#define OFF_STATS (8388608 + 1393920 + 294912)

__device__ __forceinline__ unsigned short f2bf(float f) {
    unsigned u = __builtin_bit_cast(unsigned, f);
    u = (u + 0x7FFFu + ((u >> 16) & 1u)) >> 16;
    return (unsigned short)u;
}
__device__ __forceinline__ float bf2f(unsigned short h) {
    return __builtin_bit_cast(float, (unsigned)h << 16);
}

// ---------------------------------------------------------------------------
// prep_w: conv_w [e*256+c][i(32)][tap(9)] fp32 -> wTb[e][tap][cout][i] bf16.
// LDS-staged: coalesced float4 reads, coalesced ushort writes.
// Block = (e, 32 couts); 64 blocks. Block 0 also zeroes stats.
// ---------------------------------------------------------------------------
__global__ void prep_w(const float* __restrict__ w, unsigned short* __restrict__ wTb,
                       float* __restrict__ stats) {
    __shared__ float ls[32 * 288];
    const int tid = threadIdx.x;
    const int e   = blockIdx.x >> 3;
    const int cb  = (blockIdx.x & 7) * 32;
    if (blockIdx.x == 0 && tid < NPAIR * NG * 2) stats[tid] = 0.f;
    const float4* src = (const float4*)(w + (size_t)(e * 256 + cb) * 288);
    for (int f = tid; f < 2304; f += 256) ((float4*)ls)[f] = src[f];
    __syncthreads();
    for (int idx = tid; idx < 9216; idx += 256) {
        int tap = idx >> 10;
        int rem = idx & 1023;
        int cc  = rem >> 5;
        int i   = rem & 31;
        wTb[((size_t)(e * 9 + tap) * 256 + cb + cc) * 32 + i] = f2bf(ls[cc * 288 + i * 9 + tap]);
    }
}

// ---------------------------------------------------------------------------
// prep_x: gather selected expert slice, transpose to xtp[p][row66][col66][XSTR]
// bf16 with halo zeros (rows/cols 0 and 65). Pad elems 32..39 left garbage
// (never read). One block = one (p, padded row).
// ---------------------------------------------------------------------------
__global__ void prep_x(const float* __restrict__ x, const int* __restrict__ ridx,
                       unsigned short* __restrict__ xtp) {
    __shared__ float t[32][65];
    const int r   = blockIdx.x;       // 0..65
    const int p   = blockIdx.y;       // 0..15
    const int b   = p >> 1;
    const int e   = ridx[p];
    const int tid = threadIdx.x;
    const bool inter = (r >= 1 && r <= 64);
    if (inter) {
        const float* xb = x + (((size_t)b * 256 + e * 32) * 64 + (r - 1)) * 64;
        for (int f = tid; f < 2048; f += 256)
            t[f >> 6][f & 63] = xb[(size_t)(f >> 6) * 4096 + (f & 63)];
    }
    __syncthreads();
    unsigned short* ob = xtp + ((size_t)p * 66 + r) * (66 * XSTR);
    for (int f = tid; f < 1056; f += 256) {            // 66 cols x 16 ch-pairs
        int c = f >> 4, chp = f & 15;
        ushort2 v = make_ushort2(0, 0);
        if (inter && c >= 1 && c <= 64)
            v = make_ushort2(f2bf(t[2 * chp][c - 1]), f2bf(t[2 * chp + 1][c - 1]));
        *(ushort2*)(ob + c * XSTR + chp * 2) = v;
    }
}

// ---------------------------------------------------------------------------
// conv_mfma: block = 256 cout x 128 spatial (2 image rows), 512 thr (8 waves:
// 4 cout-waves x 2 row-waves, each 64x64). K = 9 taps x 32 ch.
// Swapped operands: D = X(A) * W(B) -> acc regs = 4 consecutive spatial.
// X from LDS (80B cell stride: uniform banks); W frags double-buffered from L2.
// ---------------------------------------------------------------------------
__launch_bounds__(512, 4)
__global__ void conv_mfma(const unsigned short* __restrict__ xtp,
                          const unsigned short* __restrict__ wTb,
                          const int* __restrict__ ridx,
                          unsigned short* __restrict__ convbuf,
                          float* __restrict__ stats)
{
    __shared__ short xs[4 * 66 * XSTR];     // 21120 B

    const int tid = threadIdx.x;
    const int st  = blockIdx.x;             // 0..31 (2 image rows each)
    const int p   = blockIdx.y;             // 0..15
    const int e   = ridx[p];

    {   // stage 4 padded rows (incl. halo) = linear 21 KB copy
        const unsigned short* g = xtp + ((size_t)p * 66 + st * 2) * (66 * XSTR);
        for (int f = tid; f < 1320; f += 512)
            *(bf8_t*)&xs[f * 8] = *(const bf8_t*)(g + f * 8);
    }
    __syncthreads();

    const int lane = tid & 63;
    const int l15  = lane & 15;
    const int oct  = lane >> 4;
    const int wave = tid >> 6;
    const int wc   = wave & 3;              // cout-wave (64 couts)
    const int ws   = wave >> 2;             // image-row-wave

    // A (x) frag: lane l15 = spatial col (within 16), oct = k-chunk
    const short* Ab = xs + (ws * 66 + l15) * XSTR + oct * 8;
    // B (w) frag: lane l15 = cout (within 16), oct = k-chunk
    const unsigned short* Bb = wTb + ((size_t)e * 9 * 256 + wc * 64 + l15) * 32 + oct * 8;

    f4_t acc[4][4];
    #pragma unroll
    for (int mi = 0; mi < 4; ++mi)
        #pragma unroll
        for (int ni = 0; ni < 4; ++ni)
            acc[mi][ni] = (f4_t){0.f, 0.f, 0.f, 0.f};

    bf8_t bw[2][4];
    #pragma unroll
    for (int ni = 0; ni < 4; ++ni)
        bw[0][ni] = *(const bf8_t*)(Bb + ni * 512);

    #pragma unroll
    for (int tap = 0; tap < 9; ++tap) {
        const int dy = tap / 3, dx = tap % 3;
        if (tap < 8) {
            #pragma unroll
            for (int ni = 0; ni < 4; ++ni)
                bw[(tap + 1) & 1][ni] = *(const bf8_t*)(Bb + (tap + 1) * 8192 + ni * 512);
        }
        bf8_t ax[4];
        #pragma unroll
        for (int mi = 0; mi < 4; ++mi)
            ax[mi] = *(const bf8_t*)(Ab + (dy * 66 + mi * 16 + dx) * XSTR);
        #pragma unroll
        for (int mi = 0; mi < 4; ++mi)
            #pragma unroll
            for (int ni = 0; ni < 4; ++ni)
                acc[mi][ni] = __builtin_amdgcn_mfma_f32_16x16x32_bf16(
                    ax[mi], bw[tap & 1][ni], acc[mi][ni], 0, 0, 0);
    }

    // epilogue: 8B vectorized bf16 stores + GN partial stats
    const int sp0 = st * 128 + ws * 64 + oct * 4;
    float s0 = 0.f, q0 = 0.f, s1 = 0.f, q1 = 0.f;
    #pragma unroll
    for (int ni = 0; ni < 4; ++ni) {
        const size_t crow = ((size_t)p * 256 + wc * 64 + ni * 16 + l15) * 4096;
        #pragma unroll
        for (int mi = 0; mi < 4; ++mi) {
            float a0 = acc[mi][ni][0], a1 = acc[mi][ni][1];
            float a2 = acc[mi][ni][2], a3 = acc[mi][ni][3];
            ushort4 pk = make_ushort4(f2bf(a0), f2bf(a1), f2bf(a2), f2bf(a3));
            *(ushort4*)(convbuf + crow + sp0 + mi * 16) = pk;
            float sl = a0 + a1 + a2 + a3;
            float ql = fmaf(a0, a0, fmaf(a1, a1, fmaf(a2, a2, a3 * a3)));
            if (ni < 2) { s0 += sl; q0 += ql; }
            else        { s1 += sl; q1 += ql; }
        }
    }
    #pragma unroll
    for (int m = 32; m >= 1; m >>= 1) {
        s0 += __shfl_xor(s0, m); q0 += __shfl_xor(q0, m);
        s1 += __shfl_xor(s1, m); q1 += __shfl_xor(q1, m);
    }
    if (lane == 0) {
        int g0 = wc * 2;
        atomicAdd(&stats[(p * 8 + g0) * 2 + 0], s0);
        atomicAdd(&stats[(p * 8 + g0) * 2 + 1], q0);
        atomicAdd(&stats[(p * 8 + g0 + 1) * 2 + 0], s1);
        atomicAdd(&stats[(p * 8 + g0 + 1) * 2 + 1], q1);
    }
}

// ---------------------------------------------------------------------------
// finalize: GN (from stats) + affine + SiLU + weighted top-k combine.
// Block = (cout, b); per-k coefficients hoisted out of the spatial loop.
// ---------------------------------------------------------------------------
__global__ void finalize_k(const unsigned short* __restrict__ conv,
                           const float* __restrict__ stats,
                           const int* __restrict__ ridx,
                           const float* __restrict__ rw,
                           const float* __restrict__ gamma,
                           const float* __restrict__ beta,
                           float* __restrict__ out)
{
    const int tid = threadIdx.x;
    const int c   = blockIdx.x;        // 0..255
    const int b   = blockIdx.y;        // 0..7
    const int g   = c >> 5;

    float ga[2], be[2], wk[2];
    const unsigned short* cb[2];
    #pragma unroll
    for (int k = 0; k < KTOP; ++k) {
        int p = b * KTOP + k;
        int e = ridx[p];
        wk[k] = rw[p];
        float s  = stats[(p * 8 + g) * 2 + 0];
        float sq = stats[(p * 8 + g) * 2 + 1];
        const float cnt = 1.f / 131072.f;
        float mu  = s * cnt;
        float var = fmaf(-mu, mu, sq * cnt);
        float inv = rsqrtf(var + EPSV);
        ga[k] = gamma[e * 256 + c] * inv;
        be[k] = fmaf(-mu, ga[k], beta[e * 256 + c]);
        cb[k] = conv + ((size_t)p * 256 + c) * 4096;
    }
    float* ob = out + ((size_t)b * 256 + c) * 4096;
    #pragma unroll
    for (int j = 0; j < 4; ++j) {
        int sp = j * 1024 + tid * 4;
        float r0 = 0.f, r1 = 0.f, r2 = 0.f, r3 = 0.f;
        #pragma unroll
        for (int k = 0; k < KTOP; ++k) {
            ushort4 v = *(const ushort4*)(cb[k] + sp);
            float n0 = fmaf(bf2f(v.x), ga[k], be[k]);
            float n1 = fmaf(bf2f(v.y), ga[k], be[k]);
            float n2 = fmaf(bf2f(v.z), ga[k], be[k]);
            float n3 = fmaf(bf2f(v.w), ga[k], be[k]);
            r0 = fmaf(wk[k] * n0, 1.f / (1.f + __expf(-n0)), r0);
            r1 = fmaf(wk[k] * n1, 1.f / (1.f + __expf(-n1)), r1);
            r2 = fmaf(wk[k] * n2, 1.f / (1.f + __expf(-n2)), r2);
            r3 = fmaf(wk[k] * n3, 1.f / (1.f + __expf(-n3)), r3);
        }
        *(float4*)(ob + sp) = make_float4(r0, r1, r2, r3);
    }
}

// ---------------------------------------------------------------------------
extern "C" void kernel_launch(void* const* d_in, const int* in_sizes, int n_in,
                              void* d_out, int out_size, void* d_ws, size_t ws_size,
                              hipStream_t stream) {
    const float* x      = (const float*)d_in[0];
    const float* rw     = (const float*)d_in[1];
    const int*   ridx   = (const int*)  d_in[2];
    const float* conv_w = (const float*)d_in[4];
    const float* gamma  = (const float*)d_in[5];
    const float* beta   = (const float*)d_in[6];
    float* out = (float*)d_out;

    float* ws = (float*)d_ws;
    unsigned short* convbuf = (unsigned short*)(ws + OFF_CONV);
    unsigned short* xtp     = (unsigned short*)(ws + OFF_XTP);
    unsigned short* wTb     = (unsigned short*)(ws + OFF_WTB);
    float*          stats   = ws + OFF_STATS;

    hipLaunchKernelGGL(prep_w, dim3(64), dim3(256), 0, stream, conv_w, wTb, stats);
    hipLaunchKernelGGL(prep_x, dim3(66, 16), dim3(256), 0, stream, x, ridx, xtp);
    hipLaunchKernelGGL(conv_mfma, dim3(32, 16), dim3(512), 0, stream,
                       xtp, wTb, ridx, convbuf, stats);
    hipLaunchKernelGGL(finalize_k, dim3(256, 8), dim3(256), 0, stream,
                       convbuf, stats, ridx, rw, gamma, beta, out);
}

// Round 4
// 150.593 us; speedup vs baseline: 1.6673x; 1.0790x over previous
//
#include <hip/hip_runtime.h>

typedef __attribute__((ext_vector_type(8))) short bf8_t;   // 8 bf16 (4 VGPRs)
typedef __attribute__((ext_vector_type(4))) float f4_t;

#define KTOP  2
#define NPAIR 16
#define NG    8
#define EPSV  1e-5f
#define XSTR  40     // padded elems per (row,col) cell: 80 B -> near-uniform LDS banks

// ws layout (float units):
//  xtp   (ushort): 16*66*66*40 = 2,787,840 us -> 1,393,920 f
//  wTb   (ushort): 8*9*256*32  =   589,824 us ->   294,912 f
//  stats (float) : 16*8*2      =         256 f
#define OFF_XTP   0
#define OFF_WTB   1393920
#define OFF_STATS (1393920 + 294912)

__device__ __forceinline__ unsigned short f2bf(float f) {
    unsigned u = __builtin_bit_cast(unsigned, f);
    u = (u + 0x7FFFu + ((u >> 16) & 1u)) >> 16;
    return (unsigned short)u;
}

// ---------------------------------------------------------------------------
// prep (fused): blocks [0,64)   : conv_w -> wTb[e][tap][cout][i] bf16 (+zero stats)
//               blocks [64,1120): x gather+transpose -> xtp[p][row66][col66][XSTR]
// ---------------------------------------------------------------------------
__global__ void prep(const float* __restrict__ w, const float* __restrict__ x,
                     const int* __restrict__ ridx,
                     unsigned short* __restrict__ wTb,
                     unsigned short* __restrict__ xtp,
                     float* __restrict__ stats)
{
    __shared__ float sh[32 * 288];
    const int tid = threadIdx.x;
    if (blockIdx.x < 64) {
        const int e  = blockIdx.x >> 3;
        const int cb = (blockIdx.x & 7) * 32;
        if (blockIdx.x == 0 && tid < NPAIR * NG * 2) stats[tid] = 0.f;
        const float4* src = (const float4*)(w + (size_t)(e * 256 + cb) * 288);
        for (int f = tid; f < 2304; f += 256) ((float4*)sh)[f] = src[f];
        __syncthreads();
        for (int idx = tid; idx < 9216; idx += 256) {
            int tap = idx >> 10, rem = idx & 1023, cc = rem >> 5, i = rem & 31;
            wTb[((size_t)(e * 9 + tap) * 256 + cb + cc) * 32 + i] =
                f2bf(sh[cc * 288 + i * 9 + tap]);
        }
    } else {
        float (*t)[65] = (float(*)[65])sh;
        const int idx = blockIdx.x - 64;
        const int p   = idx / 66;
        const int r   = idx - p * 66;         // 0..65 padded row
        const int b   = p >> 1;
        const int e   = ridx[p];
        const bool inter = (r >= 1 && r <= 64);
        if (inter) {
            const float* xb = x + (((size_t)b * 256 + e * 32) * 64 + (r - 1)) * 64;
            for (int f = tid; f < 2048; f += 256)
                t[f >> 6][f & 63] = xb[(size_t)(f >> 6) * 4096 + (f & 63)];
        }
        __syncthreads();
        unsigned short* ob = xtp + ((size_t)p * 66 + r) * (66 * XSTR);
        for (int f = tid; f < 1056; f += 256) {       // 66 cols x 16 ch-pairs
            int c = f >> 4, chp = f & 15;
            ushort2 v = make_ushort2(0, 0);
            if (inter && c >= 1 && c <= 64)
                v = make_ushort2(f2bf(t[2 * chp][c - 1]), f2bf(t[2 * chp + 1][c - 1]));
            *(ushort2*)(ob + c * XSTR + chp * 2) = v;
        }
    }
}

// ---------------------------------------------------------------------------
// conv_stats: conv (A=x, B=w) -> GN partial sums only. No conv output stored.
// Block = 256 cout x 128 spatial (2 rows), 512 thr = 4 cout-waves x 2 row-waves.
// ---------------------------------------------------------------------------
__launch_bounds__(512, 4)
__global__ void conv_stats(const unsigned short* __restrict__ xtp,
                           const unsigned short* __restrict__ wTb,
                           const int* __restrict__ ridx,
                           float* __restrict__ stats)
{
    __shared__ short xs[4 * 66 * XSTR];     // 21120 B

    const int tid = threadIdx.x;
    const int st  = blockIdx.x;             // 0..31 (2 image rows)
    const int p   = blockIdx.y;             // 0..15
    const int e   = ridx[p];

    {
        const unsigned short* g = xtp + ((size_t)p * 66 + st * 2) * (66 * XSTR);
        for (int f = tid; f < 1320; f += 512)
            *(bf8_t*)&xs[f * 8] = *(const bf8_t*)(g + f * 8);
    }
    __syncthreads();

    const int lane = tid & 63, l15 = lane & 15, oct = lane >> 4;
    const int wave = tid >> 6, wc = wave & 3, wsp = wave >> 2;

    const short* Ab = xs + (wsp * 66 + l15) * XSTR + oct * 8;
    const unsigned short* Bb = wTb + ((size_t)e * 9 * 256 + wc * 64 + l15) * 32 + oct * 8;

    f4_t acc[4][4];
    #pragma unroll
    for (int mi = 0; mi < 4; ++mi)
        #pragma unroll
        for (int ni = 0; ni < 4; ++ni)
            acc[mi][ni] = (f4_t){0.f, 0.f, 0.f, 0.f};

    #pragma unroll
    for (int tap = 0; tap < 9; ++tap) {
        const int dy = tap / 3, dx = tap % 3;
        bf8_t ax[4], bw[4];
        #pragma unroll
        for (int mi = 0; mi < 4; ++mi)
            ax[mi] = *(const bf8_t*)(Ab + (dy * 66 + mi * 16 + dx) * XSTR);
        #pragma unroll
        for (int ni = 0; ni < 4; ++ni)
            bw[ni] = *(const bf8_t*)(Bb + tap * 8192 + ni * 512);
        #pragma unroll
        for (int mi = 0; mi < 4; ++mi)
            #pragma unroll
            for (int ni = 0; ni < 4; ++ni)
                acc[mi][ni] = __builtin_amdgcn_mfma_f32_16x16x32_bf16(
                    ax[mi], bw[ni], acc[mi][ni], 0, 0, 0);
    }

    float s0 = 0.f, q0 = 0.f, s1 = 0.f, q1 = 0.f;
    #pragma unroll
    for (int mi = 0; mi < 4; ++mi)
        #pragma unroll
        for (int ni = 0; ni < 4; ++ni)
            #pragma unroll
            for (int r = 0; r < 4; ++r) {
                float v = acc[mi][ni][r];
                if (ni < 2) { s0 += v; q0 = fmaf(v, v, q0); }
                else        { s1 += v; q1 = fmaf(v, v, q1); }
            }
    #pragma unroll
    for (int m = 32; m >= 1; m >>= 1) {
        s0 += __shfl_xor(s0, m); q0 += __shfl_xor(q0, m);
        s1 += __shfl_xor(s1, m); q1 += __shfl_xor(q1, m);
    }
    if (lane == 0) {
        int g0 = wc * 2;
        atomicAdd(&stats[(p * 8 + g0) * 2 + 0], s0);
        atomicAdd(&stats[(p * 8 + g0) * 2 + 1], q0);
        atomicAdd(&stats[(p * 8 + g0 + 1) * 2 + 0], s1);
        atomicAdd(&stats[(p * 8 + g0 + 1) * 2 + 1], q1);
    }
}

// ---------------------------------------------------------------------------
// conv_apply: recompute conv (A=w, B=x -> D rows = cout), GN+SiLU+combine
// over both top-k pairs, write fp32 out directly (64 B-segment dword stores).
// Block = (st, b): 2 image rows x 256 cout x both k. 8 waves as above.
// ---------------------------------------------------------------------------
__launch_bounds__(512, 2)
__global__ void conv_apply(const unsigned short* __restrict__ xtp,
                           const unsigned short* __restrict__ wTb,
                           const int* __restrict__ ridx,
                           const float* __restrict__ rw,
                           const float* __restrict__ gamma,
                           const float* __restrict__ beta,
                           const float* __restrict__ stats,
                           float* __restrict__ out)
{
    __shared__ short  xs[2][4 * 66 * XSTR];   // 42240 B
    __shared__ float2 gab[2][256];            //  4096 B

    const int tid = threadIdx.x;
    const int st  = blockIdx.x;               // 0..31
    const int b   = blockIdx.y;               // 0..7

    // stage per-cout GN coefficients: ga = gamma*inv, be = beta - mu*ga
    {
        int k = tid >> 8, c = tid & 255;
        int p = b * KTOP + k;
        int e = ridx[p];
        int g = c >> 5;
        float s  = stats[(p * 8 + g) * 2 + 0];
        float q  = stats[(p * 8 + g) * 2 + 1];
        const float cnt = 1.f / 131072.f;
        float mu  = s * cnt;
        float var = fmaf(-mu, mu, q * cnt);
        float inv = rsqrtf(var + EPSV);
        float ga  = gamma[e * 256 + c] * inv;
        float be  = fmaf(-mu, ga, beta[e * 256 + c]);
        gab[k][c] = make_float2(ga, be);
    }
    // stage x tiles for both pairs (linear copies)
    {
        const unsigned short* g0 = xtp + ((size_t)(b * KTOP + 0) * 66 + st * 2) * (66 * XSTR);
        const unsigned short* g1 = xtp + ((size_t)(b * KTOP + 1) * 66 + st * 2) * (66 * XSTR);
        for (int f = tid; f < 2640; f += 512) {
            const unsigned short* s = (f < 1320) ? (g0 + f * 8) : (g1 + (f - 1320) * 8);
            *(bf8_t*)&xs[0][f * 8] = *(const bf8_t*)s;
        }
    }
    __syncthreads();

    const int lane = tid & 63, l15 = lane & 15, oct = lane >> 4;
    const int wave = tid >> 6, wc = wave & 3, wsp = wave >> 2;

    f4_t res[4][4];
    #pragma unroll
    for (int mi = 0; mi < 4; ++mi)
        #pragma unroll
        for (int ni = 0; ni < 4; ++ni)
            res[mi][ni] = (f4_t){0.f, 0.f, 0.f, 0.f};

    #pragma unroll
    for (int k = 0; k < KTOP; ++k) {
        const int p = b * KTOP + k;
        const int e = ridx[p];
        const unsigned short* Ab = wTb + ((size_t)e * 9 * 256 + wc * 64 + l15) * 32 + oct * 8;
        const short* Bb = &xs[k][0] + (wsp * 66 + l15) * XSTR + oct * 8;

        f4_t acc[4][4];
        #pragma unroll
        for (int mi = 0; mi < 4; ++mi)
            #pragma unroll
            for (int ni = 0; ni < 4; ++ni)
                acc[mi][ni] = (f4_t){0.f, 0.f, 0.f, 0.f};

        #pragma unroll
        for (int tap = 0; tap < 9; ++tap) {
            const int dy = tap / 3, dx = tap % 3;
            bf8_t aw[4], bx[4];
            #pragma unroll
            for (int mi = 0; mi < 4; ++mi)
                aw[mi] = *(const bf8_t*)(Ab + tap * 8192 + mi * 512);
            #pragma unroll
            for (int ni = 0; ni < 4; ++ni)
                bx[ni] = *(const bf8_t*)(Bb + (dy * 66 + ni * 16 + dx) * XSTR);
            #pragma unroll
            for (int mi = 0; mi < 4; ++mi)
                #pragma unroll
                for (int ni = 0; ni < 4; ++ni)
                    acc[mi][ni] = __builtin_amdgcn_mfma_f32_16x16x32_bf16(
                        aw[mi], bx[ni], acc[mi][ni], 0, 0, 0);
        }

        const float wk = rw[p];
        #pragma unroll
        for (int mi = 0; mi < 4; ++mi) {
            float2 gb[4];
            #pragma unroll
            for (int r = 0; r < 4; ++r)
                gb[r] = gab[k][wc * 64 + mi * 16 + oct * 4 + r];
            #pragma unroll
            for (int ni = 0; ni < 4; ++ni)
                #pragma unroll
                for (int r = 0; r < 4; ++r) {
                    float n  = fmaf(acc[mi][ni][r], gb[r].x, gb[r].y);
                    float sg = __builtin_amdgcn_rcpf(1.f + __expf(-n));
                    res[mi][ni][r] = fmaf(wk * n, sg, res[mi][ni][r]);
                }
        }
    }

    // store: per (mi,r): 4 ni-stores cover 256 B/row contiguously; lanes l15
    // give 64 B segments, oct gives 4 cout rows -> clean coalescing.
    const int row = st * 2 + wsp;
    #pragma unroll
    for (int mi = 0; mi < 4; ++mi)
        #pragma unroll
        for (int r = 0; r < 4; ++r) {
            float* ob = out + ((size_t)(b * 256 + wc * 64 + mi * 16 + oct * 4 + r)) * 4096
                            + row * 64 + l15;
            #pragma unroll
            for (int ni = 0; ni < 4; ++ni)
                ob[ni * 16] = res[mi][ni][r];
        }
}

// ---------------------------------------------------------------------------
extern "C" void kernel_launch(void* const* d_in, const int* in_sizes, int n_in,
                              void* d_out, int out_size, void* d_ws, size_t ws_size,
                              hipStream_t stream) {
    const float* x      = (const float*)d_in[0];
    const float* rw     = (const float*)d_in[1];
    const int*   ridx   = (const int*)  d_in[2];
    const float* conv_w = (const float*)d_in[4];
    const float* gamma  = (const float*)d_in[5];
    const float* beta   = (const float*)d_in[6];
    float* out = (float*)d_out;

    float* ws = (float*)d_ws;
    unsigned short* xtp   = (unsigned short*)(ws + OFF_XTP);
    unsigned short* wTb   = (unsigned short*)(ws + OFF_WTB);
    float*          stats = ws + OFF_STATS;

    hipLaunchKernelGGL(prep, dim3(64 + 16 * 66), dim3(256), 0, stream,
                       conv_w, x, ridx, wTb, xtp, stats);
    hipLaunchKernelGGL(conv_stats, dim3(32, 16), dim3(512), 0, stream,
                       xtp, wTb, ridx, stats);
    hipLaunchKernelGGL(conv_apply, dim3(32, 8), dim3(512), 0, stream,
                       xtp, wTb, ridx, rw, gamma, beta, stats, out);
}